// Round 5
// baseline (663.383 us; speedup 1.0000x reference)
//
#include <hip/hip_runtime.h>

#define N_NODES 100000
#define N_EDGES 1600000
#define N_LABEL 200000
#define C_IN 128
#define C_HID 256
#define C_OUT 128

#define SCAN_NB ((N_NODES + 1023) / 1024)  // 98
#define BCHUNK 64                          // nodes per fill bucket
#define NBUCK ((N_NODES + BCHUNK - 1) / BCHUNK)  // 1563

typedef __attribute__((ext_vector_type(8))) short bf16x8;
typedef __attribute__((ext_vector_type(4))) float f32x4;

__device__ __forceinline__ ushort f2bf(float f) {  // RTNE
  uint u = __float_as_uint(f);
  return (ushort)((u + 0x7fffu + ((u >> 16) & 1u)) >> 16);
}

__device__ __forceinline__ void async_copy16(const void* g, void* lds) {
  __builtin_amdgcn_global_load_lds((const __attribute__((address_space(1))) void*)g,
                                   (__attribute__((address_space(3))) void*)lds,
                                   16, 0, 0);
}

// ---------------------------------------------------------------------------
// CSR build: histogram + 3-phase scan
// ---------------------------------------------------------------------------
__global__ __launch_bounds__(256) void hist_kernel(const int* __restrict__ dst,
                                                   int* __restrict__ counts) {
  int e = blockIdx.x * 256 + threadIdx.x;
  if (e < N_EDGES) atomicAdd(&counts[dst[e]], 1);
}

__global__ __launch_bounds__(256) void scan_p1(const int* __restrict__ counts,
                                               int* __restrict__ bsum) {
  __shared__ int red[256];
  const int t = threadIdx.x;
  const int idx = blockIdx.x * 1024 + t * 4;
  int s = 0;
  if (idx + 3 < N_NODES) {
    const int4 v = *(const int4*)&counts[idx];
    s = v.x + v.y + v.z + v.w;
  } else {
    for (int j = 0; j < 4 && idx + j < N_NODES; ++j) s += counts[idx + j];
  }
  red[t] = s;
  __syncthreads();
  for (int off = 128; off > 0; off >>= 1) {
    if (t < off) red[t] += red[t + off];
    __syncthreads();
  }
  if (t == 0) bsum[blockIdx.x] = red[0];
}

__global__ __launch_bounds__(128) void scan_p2(const int* __restrict__ bsum,
                                               int* __restrict__ bpre,
                                               int* __restrict__ row_start) {
  __shared__ int sh[128];
  const int t = threadIdx.x;
  sh[t] = (t < SCAN_NB) ? bsum[t] : 0;
  __syncthreads();
  for (int off = 1; off < 128; off <<= 1) {
    int v = 0;
    if (t >= off) v = sh[t - off];
    __syncthreads();
    if (t >= off) sh[t] += v;
    __syncthreads();
  }
  if (t < SCAN_NB) bpre[t] = (t == 0) ? 0 : sh[t - 1];
  if (t == SCAN_NB - 1) row_start[N_NODES] = sh[t];
}

__global__ __launch_bounds__(256) void scan_p3(int* __restrict__ counts,
                                               const int* __restrict__ bpre,
                                               int* __restrict__ row_start) {
  __shared__ int sh[256];
  const int t = threadIdx.x;
  const int idx = blockIdx.x * 1024 + t * 4;
  int4 v = make_int4(0, 0, 0, 0);
  const bool full = (idx + 3 < N_NODES);
  if (full) {
    v = *(const int4*)&counts[idx];
  } else {
    if (idx + 0 < N_NODES) v.x = counts[idx + 0];
    if (idx + 1 < N_NODES) v.y = counts[idx + 1];
    if (idx + 2 < N_NODES) v.z = counts[idx + 2];
    if (idx + 3 < N_NODES) v.w = counts[idx + 3];
  }
  const int tsum = v.x + v.y + v.z + v.w;
  sh[t] = tsum;
  __syncthreads();
  for (int off = 1; off < 256; off <<= 1) {
    int u = 0;
    if (t >= off) u = sh[t - off];
    __syncthreads();
    if (t >= off) sh[t] += u;
    __syncthreads();
  }
  int base = bpre[blockIdx.x] + ((t == 0) ? 0 : sh[t - 1]);
  int4 e;
  e.x = base;
  e.y = base + v.x;
  e.z = base + v.x + v.y;
  e.w = base + v.x + v.y + v.z;
  if (full) {
    *(int4*)&row_start[idx] = e;
  } else {
    if (idx + 0 < N_NODES) row_start[idx + 0] = e.x;
    if (idx + 1 < N_NODES) row_start[idx + 1] = e.y;
    if (idx + 2 < N_NODES) row_start[idx + 2] = e.z;
    if (idx + 3 < N_NODES) row_start[idx + 3] = e.w;
  }
}

// ---------------------------------------------------------------------------
// Two-phase bucketed CSR fill.
// Phase A: scatter edges to per-bucket contiguous regions (cursor-ordered, so
// writes within a bucket are dense). Entry = (src<<6)|(dst&63), 4B.
// Phase B: one block per bucket; node cursors in LDS; final in-bucket scatter
// lands in a ~4KB csr region (L2-resident lines, densely filled).
// ---------------------------------------------------------------------------
__global__ __launch_bounds__(256) void init_bcur(const int* __restrict__ row_start,
                                                 int* __restrict__ bcur) {
  int b = blockIdx.x * 256 + threadIdx.x;
  if (b < NBUCK) bcur[b] = row_start[min(b * BCHUNK, N_NODES)];
}

__global__ __launch_bounds__(256) void fill_a(const int* __restrict__ src,
                                              const int* __restrict__ dst,
                                              int* __restrict__ bcur,
                                              int* __restrict__ tmp) {
  int e = blockIdx.x * 256 + threadIdx.x;
  if (e < N_EDGES) {
    const int d = dst[e];
    const int pos = atomicAdd(&bcur[d >> 6], 1);
    tmp[pos] = (src[e] << 6) | (d & 63);
  }
}

__global__ __launch_bounds__(256) void fill_b(const int* __restrict__ row_start,
                                              const int* __restrict__ tmp,
                                              int* __restrict__ csr_src) {
  __shared__ int lcur[BCHUNK];
  const int b = blockIdx.x;
  const int lo = b * BCHUNK;
  const int hi = min(lo + BCHUNK, N_NODES);
  const int t = threadIdx.x;
  if (t < hi - lo) lcur[t] = row_start[lo + t];
  __syncthreads();
  const int s = row_start[lo];
  const int e = row_start[hi];
  for (int j = s + t; j < e; j += 256) {
    const int v = tmp[j];
    const int pos = atomicAdd(&lcur[v & 63], 1);
    csr_src[pos] = v >> 6;
  }
}

// ---------------------------------------------------------------------------
// fp32 -> bf16 cast (8 elems / thread)
// ---------------------------------------------------------------------------
__global__ __launch_bounds__(256) void cast_bf16(const float* __restrict__ in,
                                                 ushort* __restrict__ out) {
  const size_t i = ((size_t)blockIdx.x * 256 + threadIdx.x) * 8;
  const float4 a = *(const float4*)&in[i];
  const float4 b = *(const float4*)&in[i + 4];
  uint4 o;
  o.x = (uint)f2bf(a.x) | ((uint)f2bf(a.y) << 16);
  o.y = (uint)f2bf(a.z) | ((uint)f2bf(a.w) << 16);
  o.z = (uint)f2bf(b.x) | ((uint)f2bf(b.y) << 16);
  o.w = (uint)f2bf(b.z) | ((uint)f2bf(b.w) << 16);
  *(uint4*)&out[i] = o;
}

// ---------------------------------------------------------------------------
// Weight prep (N-major bf16)
// ---------------------------------------------------------------------------
__global__ __launch_bounds__(256) void prep_wt(const float* __restrict__ Wl1,
                                               const float* __restrict__ Wr1,
                                               const float* __restrict__ Wl2,
                                               const float* __restrict__ Wr2,
                                               ushort* __restrict__ WT1,
                                               ushort* __restrict__ WT2) {
  const int n = blockIdx.x;
  const int k = threadIdx.x;
  const float v1 = (k < 128) ? Wl1[k * 256 + n] : Wr1[(k - 128) * 256 + n];
  WT1[n * 256 + k] = f2bf(v1);
  const float v2 = (n < 128) ? Wl2[k * 128 + n] : Wr2[k * 128 + (n - 128)];
  WT2[n * 256 + k] = f2bf(v2);
}

// ---------------------------------------------------------------------------
// Mean aggregation by gather over bf16 rows, fp32 accumulate.
// MODE 0: write bf16 mean.  MODE 1: z[wid] += mean (fp32, in place).
// ---------------------------------------------------------------------------
template <int MODE>
__global__ __launch_bounds__(256) void gather_mean_b(const int* __restrict__ row_start,
                                                     const int* __restrict__ csr_src,
                                                     const ushort* __restrict__ feat,
                                                     ushort* __restrict__ bout,
                                                     float* __restrict__ z) {
  const int wid = blockIdx.x * 4 + (threadIdx.x >> 6);
  const int lane = threadIdx.x & 63;
  if (wid >= N_NODES) return;
  const int s = row_start[wid];
  const int e = row_start[wid + 1];
  const int c0 = lane * 2;
  float a0 = 0.f, a1 = 0.f, b0 = 0.f, b1 = 0.f;
  int j = s;
  for (; j + 1 < e; j += 2) {
    const uint v0 = *(const uint*)&feat[(size_t)csr_src[j] * 128 + c0];
    const uint v1 = *(const uint*)&feat[(size_t)csr_src[j + 1] * 128 + c0];
    a0 += __uint_as_float(v0 << 16);
    a1 += __uint_as_float(v0 & 0xffff0000u);
    b0 += __uint_as_float(v1 << 16);
    b1 += __uint_as_float(v1 & 0xffff0000u);
  }
  if (j < e) {
    const uint v0 = *(const uint*)&feat[(size_t)csr_src[j] * 128 + c0];
    a0 += __uint_as_float(v0 << 16);
    a1 += __uint_as_float(v0 & 0xffff0000u);
  }
  const float rd = 1.0f / fmaxf((float)(e - s), 1.0f);
  const float m0 = (a0 + b0) * rd;
  const float m1 = (a1 + b1) * rd;
  if (MODE == 0) {
    *(uint*)&bout[(size_t)wid * 128 + c0] = (uint)f2bf(m0) | ((uint)f2bf(m1) << 16);
  } else {
    float2 zv = *(const float2*)&z[(size_t)wid * 128 + c0];
    zv.x += m0;
    zv.y += m1;
    *(float2*)&z[(size_t)wid * 128 + c0] = zv;
  }
}

// ---------------------------------------------------------------------------
// MFMA GEMM, layer 1: h = relu([aggb|xb] @ [Wl1;Wr1] + bl1), bf16 out.
// ---------------------------------------------------------------------------
__global__ __launch_bounds__(256) void gemm_l1(const ushort* __restrict__ aggb,
                                               const ushort* __restrict__ xb,
                                               const ushort* __restrict__ WT,
                                               const float* __restrict__ bias,
                                               ushort* __restrict__ h) {
  __shared__ ushort As[4096];
  __shared__ ushort Bs[4096];
  const int tid = threadIdx.x;
  const int w = tid >> 6;
  const int l = tid & 63;
  const int row0 = blockIdx.x * 128;
  const int col0 = blockIdx.y * 128;
  const int wm = (w >> 1) * 64;
  const int wn = (w & 1) * 64;
  const int srow = l >> 2;
  const int sbyte = (l & 3) * 16;
  f32x4 acc[4][4] = {};

  for (int kc = 0; kc < 8; ++kc) {
    const ushort* Ab = (kc < 4) ? aggb : xb;
    const int kco = (kc & 3) * 64;
    const int kbo = kc * 64;
    __syncthreads();
#pragma unroll
    for (int i = 0; i < 4; ++i) {
      const int c = w * 4 + i;
      if (c < 8) {
        int gr = row0 + c * 16 + srow;
        gr = (gr < N_NODES) ? gr : (N_NODES - 1);
        async_copy16((const char*)Ab + (size_t)gr * 256 + kco + sbyte,
                     (char*)As + c * 1024);
      } else {
        const int cb = c - 8;
        const int nr = col0 + cb * 16 + srow;
        async_copy16((const char*)WT + (size_t)nr * 512 + kbo + sbyte,
                     (char*)Bs + cb * 1024);
      }
    }
    __syncthreads();
    const int fr = l & 15;
    const int kg = (l >> 4) * 8;
    bf16x8 af[4], bfr[4];
#pragma unroll
    for (int i = 0; i < 4; ++i)
      af[i] = *(const bf16x8*)&As[(wm + i * 16 + fr) * 32 + kg];
#pragma unroll
    for (int j = 0; j < 4; ++j)
      bfr[j] = *(const bf16x8*)&Bs[(wn + j * 16 + fr) * 32 + kg];
#pragma unroll
    for (int i = 0; i < 4; ++i)
#pragma unroll
      for (int j = 0; j < 4; ++j)
        acc[i][j] = __builtin_amdgcn_mfma_f32_16x16x32_bf16(af[i], bfr[j],
                                                            acc[i][j], 0, 0, 0);
  }

  const int cr = (l >> 4) * 4;
  const int cc = l & 15;
#pragma unroll
  for (int i = 0; i < 4; ++i) {
    const int growb = row0 + wm + i * 16 + cr;
#pragma unroll
    for (int j = 0; j < 4; ++j) {
      const int gcol = col0 + wn + j * 16 + cc;
      const float bv = bias[gcol];
#pragma unroll
      for (int r = 0; r < 4; ++r) {
        const int grow = growb + r;
        if (grow < N_NODES) {
          const float v = fmaxf(acc[i][j][r] + bv, 0.f);
          h[(size_t)grow * 256 + gcol] = f2bf(v);
        }
      }
    }
  }
}

// ---------------------------------------------------------------------------
// MFMA GEMM, layer 2 fused: y==0 -> p = h@Wl2 (bf16); y==1 -> zp = h@Wr2+bl2.
// ---------------------------------------------------------------------------
__global__ __launch_bounds__(256) void gemm_l2(const ushort* __restrict__ h,
                                               const ushort* __restrict__ WT,
                                               const float* __restrict__ bias,
                                               ushort* __restrict__ p,
                                               float* __restrict__ zp) {
  __shared__ ushort As[4096];
  __shared__ ushort Bs[4096];
  const int tid = threadIdx.x;
  const int w = tid >> 6;
  const int l = tid & 63;
  const int row0 = blockIdx.x * 128;
  const int col0 = blockIdx.y * 128;
  const int wm = (w >> 1) * 64;
  const int wn = (w & 1) * 64;
  const int srow = l >> 2;
  const int sbyte = (l & 3) * 16;
  f32x4 acc[4][4] = {};

  for (int kc = 0; kc < 8; ++kc) {
    const int kbo = kc * 64;
    __syncthreads();
#pragma unroll
    for (int i = 0; i < 4; ++i) {
      const int c = w * 4 + i;
      if (c < 8) {
        int gr = row0 + c * 16 + srow;
        gr = (gr < N_NODES) ? gr : (N_NODES - 1);
        async_copy16((const char*)h + (size_t)gr * 512 + kbo + sbyte,
                     (char*)As + c * 1024);
      } else {
        const int cb = c - 8;
        const int nr = col0 + cb * 16 + srow;
        async_copy16((const char*)WT + (size_t)nr * 512 + kbo + sbyte,
                     (char*)Bs + cb * 1024);
      }
    }
    __syncthreads();
    const int fr = l & 15;
    const int kg = (l >> 4) * 8;
    bf16x8 af[4], bfr[4];
#pragma unroll
    for (int i = 0; i < 4; ++i)
      af[i] = *(const bf16x8*)&As[(wm + i * 16 + fr) * 32 + kg];
#pragma unroll
    for (int j = 0; j < 4; ++j)
      bfr[j] = *(const bf16x8*)&Bs[(wn + j * 16 + fr) * 32 + kg];
#pragma unroll
    for (int i = 0; i < 4; ++i)
#pragma unroll
      for (int j = 0; j < 4; ++j)
        acc[i][j] = __builtin_amdgcn_mfma_f32_16x16x32_bf16(af[i], bfr[j],
                                                            acc[i][j], 0, 0, 0);
  }

  const int cr = (l >> 4) * 4;
  const int cc = l & 15;
  const bool is_p = (blockIdx.y == 0);
#pragma unroll
  for (int i = 0; i < 4; ++i) {
    const int growb = row0 + wm + i * 16 + cr;
#pragma unroll
    for (int j = 0; j < 4; ++j) {
      const int gcl = wn + j * 16 + cc;
      const float bv = is_p ? 0.f : bias[gcl];
#pragma unroll
      for (int r = 0; r < 4; ++r) {
        const int grow = growb + r;
        if (grow < N_NODES) {
          const float v = acc[i][j][r] + bv;
          if (is_p)
            p[(size_t)grow * 128 + gcl] = f2bf(v);
          else
            zp[(size_t)grow * 128 + gcl] = v;
        }
      }
    }
  }
}

// ---------------------------------------------------------------------------
// Decode
// ---------------------------------------------------------------------------
__global__ __launch_bounds__(256) void dot_kernel(const int* __restrict__ ls,
                                                  const int* __restrict__ ld,
                                                  const float* __restrict__ z,
                                                  float* __restrict__ out) {
  long long tid = (long long)blockIdx.x * 256 + threadIdx.x;
  int e = (int)(tid >> 5);
  int lane = (int)(tid & 31);
  if (e >= N_LABEL) return;
  int a = ls[e], b = ld[e];
  const float4 va = *(const float4*)&z[(size_t)a * 128 + lane * 4];
  const float4 vb = *(const float4*)&z[(size_t)b * 128 + lane * 4];
  float p = va.x * vb.x + va.y * vb.y + va.z * vb.z + va.w * vb.w;
  p += __shfl_xor(p, 16, 32);
  p += __shfl_xor(p, 8, 32);
  p += __shfl_xor(p, 4, 32);
  p += __shfl_xor(p, 2, 32);
  p += __shfl_xor(p, 1, 32);
  if (lane == 0) out[e] = p;
}

extern "C" void kernel_launch(void* const* d_in, const int* in_sizes, int n_in,
                              void* d_out, int out_size, void* d_ws, size_t ws_size,
                              hipStream_t stream) {
  const float* x = (const float*)d_in[0];
  const int* ei = (const int*)d_in[1];
  const int* eli = (const int*)d_in[2];
  const float* Wl1 = (const float*)d_in[3];
  const float* bl1 = (const float*)d_in[4];
  const float* Wr1 = (const float*)d_in[5];
  const float* Wl2 = (const float*)d_in[6];
  const float* bl2 = (const float*)d_in[7];
  const float* Wr2 = (const float*)d_in[8];
  float* out = (float*)d_out;

  const int* e_src = ei;
  const int* e_dst = ei + N_EDGES;
  const int* l_src = eli;
  const int* l_dst = eli + N_LABEL;

  char* ws = (char*)d_ws;
  ushort* xb = (ushort*)(ws + 0);                 //  25.6 MB
  ushort* aggb = (ushort*)(ws + 25600000);        //  25.6 MB
  ushort* h = (ushort*)(ws + 51200000);           //  51.2 MB
  ushort* p = (ushort*)(ws + 102400000);          //  25.6 MB
  float* z = (float*)(ws + 128000000);            //  51.2 MB
  ushort* WT1 = (ushort*)(ws + 179200000);        // 128 KB
  ushort* WT2 = (ushort*)(ws + 179331072);        // 128 KB
  int* row_start = (int*)(ws + 179462144);        // 400 KB
  int* csr_src = (int*)(ws + 179862272);          // 6.4 MB
  int* bsum = (int*)(ws + 186262272);
  int* bpre = bsum + 128;
  int* bcur = bpre + 128;                         // 1563 ints
  int* counts = (int*)z;    // aliases z (dead until gemm_l2 writes zp)
  int* tmp = (int*)h;       // aliases h (dead until gemm_l1; fill done before)

  // --- CSR build ---
  hipMemsetAsync(counts, 0, (size_t)N_NODES * 4, stream);
  hist_kernel<<<(N_EDGES + 255) / 256, 256, 0, stream>>>(e_dst, counts);
  scan_p1<<<SCAN_NB, 256, 0, stream>>>(counts, bsum);
  scan_p2<<<1, 128, 0, stream>>>(bsum, bpre, row_start);
  scan_p3<<<SCAN_NB, 256, 0, stream>>>(counts, bpre, row_start);
  init_bcur<<<(NBUCK + 255) / 256, 256, 0, stream>>>(row_start, bcur);
  fill_a<<<(N_EDGES + 255) / 256, 256, 0, stream>>>(e_src, e_dst, bcur, tmp);
  fill_b<<<NBUCK, 256, 0, stream>>>(row_start, tmp, csr_src);

  // --- casts / weight prep ---
  cast_bf16<<<(N_NODES * C_IN) / (256 * 8), 256, 0, stream>>>(x, xb);
  prep_wt<<<256, 256, 0, stream>>>(Wl1, Wr1, Wl2, Wr2, WT1, WT2);

  // --- layer 1 ---
  gather_mean_b<0><<<(N_NODES + 3) / 4, 256, 0, stream>>>(row_start, csr_src, xb,
                                                          aggb, nullptr);
  gemm_l1<<<dim3((N_NODES + 127) / 128, 2), 256, 0, stream>>>(aggb, xb, WT1, bl1, h);

  // --- layer 2 ---
  gemm_l2<<<dim3((N_NODES + 127) / 128, 2), 256, 0, stream>>>(h, WT2, bl2, p, z);
  gather_mean_b<1><<<(N_NODES + 3) / 4, 256, 0, stream>>>(row_start, csr_src, p,
                                                          nullptr, z);

  // --- decode ---
  dot_kernel<<<(int)(((long long)N_LABEL * 32) / 256), 256, 0, stream>>>(
      l_src, l_dst, z, out);
}